// Round 1
// baseline (93.907 us; speedup 1.0000x reference)
//
#include <hip/hip_runtime.h>

#define DT 0.025f

__global__ __launch_bounds__(256) void next_states_kernel(
    const float* __restrict__ params,
    const float* __restrict__ states,
    const float* __restrict__ actions,
    const float* __restrict__ foot_pos,
    const int*   __restrict__ contacts,
    float* __restrict__ out,
    int batch)
{
    int i = blockIdx.x * blockDim.x + threadIdx.x;
    if (i >= batch) return;

    // ---- batch-uniform params: inv_mass, inv(inertia) ----
    float p0 = params[0];
    float p1 = params[1], p2 = params[2], p3 = params[3];
    float p4 = params[4], p5 = params[5], p6 = params[6];
    float inv_mass = 1.0f / p0;
    // inertia = L L^T + 1e-5 (elementwise), L lower-triangular from p1..p6
    float a00 = p1*p1 + 1e-5f;
    float a01 = p1*p2 + 1e-5f;
    float a02 = p1*p4 + 1e-5f;
    float a11 = p2*p2 + p3*p3 + 1e-5f;
    float a12 = p2*p4 + p3*p5 + 1e-5f;
    float a22 = p4*p4 + p5*p5 + p6*p6 + 1e-5f;
    // symmetric 3x3 inverse via adjugate
    float c00 = a11*a22 - a12*a12;
    float c01 = a02*a12 - a01*a22;
    float c02 = a01*a12 - a11*a02;
    float det = a00*c00 + a01*c01 + a02*c02;
    float idet = 1.0f / det;
    float i00 = c00*idet, i01 = c01*idet, i02 = c02*idet;
    float i11 = (a00*a22 - a02*a02)*idet;
    float i12 = (a02*a01 - a00*a12)*idet;
    float i22 = (a00*a11 - a01*a01)*idet;

    // ---- per-row loads ----
    const float* S = states + (size_t)i * 13;
    float s0 = S[0],  s1 = S[1],  s2 = S[2],  s3 = S[3];
    float s4 = S[4],  s5 = S[5],  s6 = S[6],  s7 = S[7];
    float s8 = S[8],  s9 = S[9],  s10 = S[10], s11 = S[11], s12 = S[12];

    const float4* A4 = (const float4*)(actions  + (size_t)i * 12);
    const float4* F4 = (const float4*)(foot_pos + (size_t)i * 12);
    float4 av0 = A4[0], av1 = A4[1], av2 = A4[2];
    float4 fv0 = F4[0], fv1 = F4[1], fv2 = F4[2];
    float act[12] = {av0.x, av0.y, av0.z, av0.w,
                     av1.x, av1.y, av1.z, av1.w,
                     av2.x, av2.y, av2.z, av2.w};
    float fpb[12] = {fv0.x, fv0.y, fv0.z, fv0.w,
                     fv1.x, fv1.y, fv1.z, fv1.w,
                     fv2.x, fv2.y, fv2.z, fv2.w};
    int4 cv = *(const int4*)(contacts + (size_t)i * 4);
    float fc[4] = {cv.x ? 1.0f : 0.0f, cv.y ? 1.0f : 0.0f,
                   cv.z ? 1.0f : 0.0f, cv.w ? 1.0f : 0.0f};

    // ---- rotation from RPY ----
    float sr, cr, sp, cp, sy, cyw;
    sincosf(s0, &sr, &cr);
    sincosf(s1, &sp, &cp);
    sincosf(s2, &sy, &cyw);

    float r00 = cyw*cp, r01 = cyw*sp*sr - sy*cr, r02 = cyw*sp*cr + sy*sr;
    float r10 = sy*cp,  r11 = sy*sp*sr + cyw*cr, r12 = sy*sp*cr - cyw*sr;
    float r20 = -sp,    r21 = cp*sr,             r22 = cp*cr;

    // ---- accumulate c = sum_f fc*(foot_world_f x a_f), fs = sum_f fc*a_f ----
    float ccx = 0.f, ccy = 0.f, ccz = 0.f;
    float fsx = 0.f, fsy = 0.f, fsz = 0.f;
#pragma unroll
    for (int f = 0; f < 4; ++f) {
        float bx = fpb[f*3+0], by = fpb[f*3+1], bz = fpb[f*3+2];
        float wx = r00*bx + r01*by + r02*bz;
        float wy = r10*bx + r11*by + r12*bz;
        float wz = r20*bx + r21*by + r22*bz;
        float ax = act[f*3+0], ay = act[f*3+1], az = act[f*3+2];
        float w = fc[f];
        ccx += w * (wy*az - wz*ay);
        ccy += w * (wz*ax - wx*az);
        ccz += w * (wx*ay - wy*ax);
        fsx += w * ax; fsy += w * ay; fsz += w * az;
    }

    // ---- t = R * invI * R^T * c ----
    float u0 = r00*ccx + r10*ccy + r20*ccz;
    float u1 = r01*ccx + r11*ccy + r21*ccz;
    float u2 = r02*ccx + r12*ccy + r22*ccz;
    float w0 = i00*u0 + i01*u1 + i02*u2;
    float w1 = i01*u0 + i11*u1 + i12*u2;
    float w2 = i02*u0 + i12*u1 + i22*u2;
    float t0 = r00*w0 + r01*w1 + r02*w2;
    float t1 = r10*w0 + r11*w1 + r12*w2;
    float t2 = r20*w0 + r21*w1 + r22*w2;

    // ---- euler-rate matrix terms ----
    float icp = 1.0f / cp;
    float tp  = sp * icp;

    float o0  = s0 + DT * ((cyw*icp)*s6 + (sy*icp)*s7);
    float o1  = s1 + DT * (cyw*s7 - sy*s6);
    float o2  = s2 + DT * ((cyw*tp)*s6 + (sy*tp)*s7 + s8);
    float o3  = s3 + DT * s9;
    float o4  = s4 + DT * s10;
    float o5  = s5 + DT * s11;
    float o6  = s6 + DT * t0;
    float o7  = s7 + DT * t1;
    float o8  = s8 + DT * t2;
    float o9  = s9  + DT * inv_mass * fsx;
    float o10 = s10 + DT * inv_mass * fsy;
    float o11 = s11 + DT * inv_mass * fsz + DT * s12;
    float o12 = s12;

    float* O = out + (size_t)i * 13;
    O[0] = o0;  O[1] = o1;  O[2] = o2;  O[3] = o3;  O[4] = o4;
    O[5] = o5;  O[6] = o6;  O[7] = o7;  O[8] = o8;  O[9] = o9;
    O[10] = o10; O[11] = o11; O[12] = o12;
}

extern "C" void kernel_launch(void* const* d_in, const int* in_sizes, int n_in,
                              void* d_out, int out_size, void* d_ws, size_t ws_size,
                              hipStream_t stream) {
    const float* params   = (const float*)d_in[0];
    const float* states   = (const float*)d_in[1];
    const float* actions  = (const float*)d_in[2];
    const float* foot_pos = (const float*)d_in[3];
    const int*   contacts = (const int*)d_in[4];
    float* out = (float*)d_out;
    int batch = in_sizes[1] / 13;
    int block = 256;
    int grid = (batch + block - 1) / block;
    next_states_kernel<<<grid, block, 0, stream>>>(
        params, states, actions, foot_pos, contacts, out, batch);
}

// Round 2
// 92.540 us; speedup vs baseline: 1.0148x; 1.0148x over previous
//
#include <hip/hip_runtime.h>

#define DT 0.025f
#define ROWS_PER_BLOCK 256

__global__ __launch_bounds__(256) void next_states_kernel(
    const float* __restrict__ params,
    const float* __restrict__ states,
    const float* __restrict__ actions,
    const float* __restrict__ foot_pos,
    const int*   __restrict__ contacts,
    float* __restrict__ out,
    int batch)
{
    __shared__ float s_st[ROWS_PER_BLOCK * 13];   // 13312 B
    __shared__ float s_ot[ROWS_PER_BLOCK * 13];   // 13312 B

    const int t = threadIdx.x;
    const int blockRow = blockIdx.x * ROWS_PER_BLOCK;
    const int rows = min(ROWS_PER_BLOCK, batch - blockRow);
    const bool full = (rows == ROWS_PER_BLOCK);

    // ---- coalesced global -> LDS staging of states (256 rows * 13 f = 832 float4) ----
    if (full) {
        const float4* gs4 = (const float4*)(states + (size_t)blockRow * 13);
        float4* ls4 = (float4*)s_st;
        ls4[t]       = gs4[t];
        ls4[t + 256] = gs4[t + 256];
        ls4[t + 512] = gs4[t + 512];
        if (t < 64) ls4[t + 768] = gs4[t + 768];
    } else {
        const int nflt = rows * 13;
        const float* gs = states + (size_t)blockRow * 13;
        for (int k = t; k < nflt; k += ROWS_PER_BLOCK) s_st[k] = gs[k];
    }
    __syncthreads();

    const int i = blockRow + t;
    if (t < rows) {
        // ---- batch-uniform params: inv_mass, inv(inertia) ----
        float p0 = params[0];
        float p1 = params[1], p2 = params[2], p3 = params[3];
        float p4 = params[4], p5 = params[5], p6 = params[6];
        float inv_mass = 1.0f / p0;
        float a00 = p1*p1 + 1e-5f;
        float a01 = p1*p2 + 1e-5f;
        float a02 = p1*p4 + 1e-5f;
        float a11 = p2*p2 + p3*p3 + 1e-5f;
        float a12 = p2*p4 + p3*p5 + 1e-5f;
        float a22 = p4*p4 + p5*p5 + p6*p6 + 1e-5f;
        float c00 = a11*a22 - a12*a12;
        float c01 = a02*a12 - a01*a22;
        float c02 = a01*a12 - a11*a02;
        float det = a00*c00 + a01*c01 + a02*c02;
        float idet = 1.0f / det;
        float i00 = c00*idet, i01 = c01*idet, i02 = c02*idet;
        float i11 = (a00*a22 - a02*a02)*idet;
        float i12 = (a02*a01 - a00*a12)*idet;
        float i22 = (a00*a11 - a01*a01)*idet;

        // ---- per-row state from LDS (stride 13 = odd -> 2 lanes/bank, free) ----
        const float* S = s_st + t * 13;
        float s0 = S[0],  s1 = S[1],  s2 = S[2],  s3 = S[3];
        float s4 = S[4],  s5 = S[5],  s6 = S[6],  s7 = S[7];
        float s8 = S[8],  s9 = S[9],  s10 = S[10], s11 = S[11], s12 = S[12];

        const float4* A4 = (const float4*)(actions  + (size_t)i * 12);
        const float4* F4 = (const float4*)(foot_pos + (size_t)i * 12);
        float4 av0 = A4[0], av1 = A4[1], av2 = A4[2];
        float4 fv0 = F4[0], fv1 = F4[1], fv2 = F4[2];
        float act[12] = {av0.x, av0.y, av0.z, av0.w,
                         av1.x, av1.y, av1.z, av1.w,
                         av2.x, av2.y, av2.z, av2.w};
        float fpb[12] = {fv0.x, fv0.y, fv0.z, fv0.w,
                         fv1.x, fv1.y, fv1.z, fv1.w,
                         fv2.x, fv2.y, fv2.z, fv2.w};
        int4 cv = *(const int4*)(contacts + (size_t)i * 4);
        float fc[4] = {cv.x ? 1.0f : 0.0f, cv.y ? 1.0f : 0.0f,
                       cv.z ? 1.0f : 0.0f, cv.w ? 1.0f : 0.0f};

        // ---- rotation from RPY ----
        float sr, cr, sp, cp, sy, cyw;
        sincosf(s0, &sr, &cr);
        sincosf(s1, &sp, &cp);
        sincosf(s2, &sy, &cyw);

        float r00 = cyw*cp, r01 = cyw*sp*sr - sy*cr, r02 = cyw*sp*cr + sy*sr;
        float r10 = sy*cp,  r11 = sy*sp*sr + cyw*cr, r12 = sy*sp*cr - cyw*sr;
        float r20 = -sp,    r21 = cp*sr,             r22 = cp*cr;

        // ---- c = sum_f fc*(foot_world_f x a_f); fs = sum_f fc*a_f ----
        float ccx = 0.f, ccy = 0.f, ccz = 0.f;
        float fsx = 0.f, fsy = 0.f, fsz = 0.f;
#pragma unroll
        for (int f = 0; f < 4; ++f) {
            float bx = fpb[f*3+0], by = fpb[f*3+1], bz = fpb[f*3+2];
            float wx = r00*bx + r01*by + r02*bz;
            float wy = r10*bx + r11*by + r12*bz;
            float wz = r20*bx + r21*by + r22*bz;
            float ax = act[f*3+0], ay = act[f*3+1], az = act[f*3+2];
            float w = fc[f];
            ccx += w * (wy*az - wz*ay);
            ccy += w * (wz*ax - wx*az);
            ccz += w * (wx*ay - wy*ax);
            fsx += w * ax; fsy += w * ay; fsz += w * az;
        }

        // ---- t = R * invI * R^T * c ----
        float u0 = r00*ccx + r10*ccy + r20*ccz;
        float u1 = r01*ccx + r11*ccy + r21*ccz;
        float u2 = r02*ccx + r12*ccy + r22*ccz;
        float w0 = i00*u0 + i01*u1 + i02*u2;
        float w1 = i01*u0 + i11*u1 + i12*u2;
        float w2 = i02*u0 + i12*u1 + i22*u2;
        float t0 = r00*w0 + r01*w1 + r02*w2;
        float t1 = r10*w0 + r11*w1 + r12*w2;
        float t2 = r20*w0 + r21*w1 + r22*w2;

        float icp = 1.0f / cp;
        float tp  = sp * icp;

        float* O = s_ot + t * 13;
        O[0]  = s0 + DT * ((cyw*icp)*s6 + (sy*icp)*s7);
        O[1]  = s1 + DT * (cyw*s7 - sy*s6);
        O[2]  = s2 + DT * ((cyw*tp)*s6 + (sy*tp)*s7 + s8);
        O[3]  = s3 + DT * s9;
        O[4]  = s4 + DT * s10;
        O[5]  = s5 + DT * s11;
        O[6]  = s6 + DT * t0;
        O[7]  = s7 + DT * t1;
        O[8]  = s8 + DT * t2;
        O[9]  = s9  + DT * inv_mass * fsx;
        O[10] = s10 + DT * inv_mass * fsy;
        O[11] = s11 + DT * inv_mass * fsz + DT * s12;
        O[12] = s12;
    }
    __syncthreads();

    // ---- coalesced LDS -> global store of out ----
    if (full) {
        float4* go4 = (float4*)(out + (size_t)blockRow * 13);
        const float4* lo4 = (const float4*)s_ot;
        go4[t]       = lo4[t];
        go4[t + 256] = lo4[t + 256];
        go4[t + 512] = lo4[t + 512];
        if (t < 64) go4[t + 768] = lo4[t + 768];
    } else {
        const int nflt = rows * 13;
        float* go = out + (size_t)blockRow * 13;
        for (int k = t; k < nflt; k += ROWS_PER_BLOCK) go[k] = s_ot[k];
    }
}

extern "C" void kernel_launch(void* const* d_in, const int* in_sizes, int n_in,
                              void* d_out, int out_size, void* d_ws, size_t ws_size,
                              hipStream_t stream) {
    const float* params   = (const float*)d_in[0];
    const float* states   = (const float*)d_in[1];
    const float* actions  = (const float*)d_in[2];
    const float* foot_pos = (const float*)d_in[3];
    const int*   contacts = (const int*)d_in[4];
    float* out = (float*)d_out;
    int batch = in_sizes[1] / 13;
    int grid = (batch + ROWS_PER_BLOCK - 1) / ROWS_PER_BLOCK;
    next_states_kernel<<<grid, ROWS_PER_BLOCK, 0, stream>>>(
        params, states, actions, foot_pos, contacts, out, batch);
}